// Round 16
// baseline (706.929 us; speedup 1.0000x reference)
//
#include <hip/hip_runtime.h>

// ---------------------------------------------------------------------------
// Problem constants (fixed by the reference)
// ---------------------------------------------------------------------------
#define TOK   4096      // B*S
#define DIM   1024
#define NQK   4096
#define NV    4096
#define NKN   8192
#define SLEN  2048
#define NH    16
#define DH    64
#define CAPA  48        // capacity for k=32 gates (slack for ties)
#define CAPK  96        // capacity for k=64 gate
#define APAD  72        // attn LDS row pad (bf16 elems): 144B keeps b128 align

typedef float  f32x4  __attribute__((ext_vector_type(4)));
typedef short  short8 __attribute__((ext_vector_type(8)));
typedef unsigned int  u32;
typedef unsigned short u16;

__device__ __forceinline__ u16 f2bf(float f) {
    u32 u = __float_as_uint(f);
    u32 r = (u + 0x7fffu + ((u >> 16) & 1u)) >> 16;
    return (u16)r;
}
__device__ __forceinline__ float bf2f(u16 v) { return __uint_as_float(((u32)v) << 16); }

// monotone bf16 -> u16 key (order-preserving over floats)
__device__ __forceinline__ u16 bfkey(u16 b) {
    return (b & 0x8000u) ? (u16)(~b) : (u16)(b | 0x8000u);
}
// inverse: key -> bf16 bits
__device__ __forceinline__ u16 keybf(u16 k) {
    return (k & 0x8000u) ? (u16)(k & 0x7fffu) : (u16)(~k);
}

__device__ __forceinline__ f32x4 mfma_bf16(short8 a, short8 b, f32x4 c) {
    asm volatile("v_mfma_f32_16x16x32_bf16 %0, %1, %2, %0"
                 : "+v"(c) : "v"(a), "v"(b));
    return c;
}

// async global->LDS, 16B per lane; LDS dest = wave-uniform base + lane*16
__device__ __forceinline__ void gload16(const u16* g, u16* s) {
    __builtin_amdgcn_global_load_lds((const __attribute__((address_space(1))) void*)g,
                                     (__attribute__((address_space(3))) void*)s, 16, 0, 0);
}

__device__ __forceinline__ float blockReduceF(float v, float* red, int wave, int lane) {
#pragma unroll
    for (int off = 32; off > 0; off >>= 1) v += __shfl_xor(v, off);
    __syncthreads();
    if (lane == 0) red[wave] = v;
    __syncthreads();
    return red[0] + red[1] + red[2] + red[3];
}

// ---------------------------------------------------------------------------
// fused f32 -> bf16 conversion of all six tables (one launch)
// ---------------------------------------------------------------------------
__global__ __launch_bounds__(256) void k_convert_all(const float* __restrict__ p0,
                                                     const float* __restrict__ p1,
                                                     const float* __restrict__ p2,
                                                     const float* __restrict__ p3,
                                                     const float* __restrict__ p4,
                                                     const float* __restrict__ p5,
                                                     u16* __restrict__ o0, u16* __restrict__ o1,
                                                     u16* __restrict__ o2, u16* __restrict__ o3,
                                                     u16* __restrict__ o4, u16* __restrict__ o5) {
    const int S0 = 1048576, S1 = 2097152, S2 = 4194304, S3 = 5242880, S4 = 6291456, S5 = 8388608;
    for (int i = blockIdx.x * 256 + threadIdx.x; i < S5; i += gridDim.x * 256) {
        const float* in; u16* out; int off;
        if (i < S0)      { in = p0; out = o0; off = i; }
        else if (i < S1) { in = p1; out = o1; off = i - S0; }
        else if (i < S2) { in = p2; out = o2; off = i - S1; }
        else if (i < S3) { in = p3; out = o3; off = i - S2; }
        else if (i < S4) { in = p4; out = o4; off = i - S3; }
        else             { in = p5; out = o5; off = i - S4; }
        float4 v = reinterpret_cast<const float4*>(in)[off];
        reinterpret_cast<ushort4*>(out)[off] = make_ushort4(f2bf(v.x), f2bf(v.y), f2bf(v.z), f2bf(v.w));
    }
}

// transpose 1024x1024 f32 -> bf16 (out[n][k] = in[k][n])
__global__ __launch_bounds__(256) void k_transpose_bf16(const float* __restrict__ in,
                                                        u16* __restrict__ out) {
    __shared__ float tile[32][33];
    int bx = blockIdx.x * 32;   // col of in
    int by = blockIdx.y * 32;   // row of in
    int tx = threadIdx.x & 31;
    int ty = threadIdx.x >> 5;  // 0..7
    for (int r = ty; r < 32; r += 8)
        tile[r][tx] = in[(size_t)(by + r) * DIM + bx + tx];
    __syncthreads();
    for (int r = ty; r < 32; r += 8)
        out[(size_t)(bx + r) * DIM + by + tx] = f2bf(tile[tx][r]);
}

// ---------------------------------------------------------------------------
// LayerNorm + tau projection; writes bf16 normed + f32 tau[t][ntau]
// ---------------------------------------------------------------------------
__global__ __launch_bounds__(256) void k_ln_tau(const float* __restrict__ x,
                                                const float* __restrict__ sc,
                                                const float* __restrict__ bi,
                                                const float* __restrict__ tauk,
                                                const float* __restrict__ taub,
                                                int ntau,
                                                u16* __restrict__ nrm,
                                                float* __restrict__ tau_out) {
    __shared__ float red[4];
    int t = blockIdx.x, tid = threadIdx.x, wave = tid >> 6, lane = tid & 63;
    const float4 xv = reinterpret_cast<const float4*>(x + (size_t)t * DIM)[tid];
    float s = xv.x + xv.y + xv.z + xv.w;
    s = blockReduceF(s, red, wave, lane);
    float mean = s * (1.0f / DIM);
    float d0 = xv.x - mean, d1 = xv.y - mean, d2 = xv.z - mean, d3 = xv.w - mean;
    float ss = d0 * d0 + d1 * d1 + d2 * d2 + d3 * d3;
    ss = blockReduceF(ss, red, wave, lane);
    float rstd = rsqrtf(ss * (1.0f / DIM) + 1e-6f);
    const float4 scv = reinterpret_cast<const float4*>(sc)[tid];
    const float4 biv = reinterpret_cast<const float4*>(bi)[tid];
    float n0 = d0 * rstd * scv.x + biv.x;
    float n1 = d1 * rstd * scv.y + biv.y;
    float n2 = d2 * rstd * scv.z + biv.z;
    float n3 = d3 * rstd * scv.w + biv.w;
    ushort4 o = make_ushort4(f2bf(n0), f2bf(n1), f2bf(n2), f2bf(n3));
    reinterpret_cast<ushort4*>(nrm + (size_t)t * DIM)[tid] = o;
    int d = tid * 4;
    for (int j = 0; j < ntau; j++) {
        float p = n0 * tauk[(size_t)(d + 0) * ntau + j] + n1 * tauk[(size_t)(d + 1) * ntau + j]
                + n2 * tauk[(size_t)(d + 2) * ntau + j] + n3 * tauk[(size_t)(d + 3) * ntau + j];
        p = blockReduceF(p, red, wave, lane);
        if (tid == 0) tau_out[(size_t)t * ntau + j] = p + taub[j];
    }
}

// ---------------------------------------------------------------------------
// C = A[M][K] @ B[N][K]^T  (bf16 in).  KEYOUT=0: f32 out (+res fuse).
// KEYOUT=1: write u16 monotone keys of bf16(score) for radix-select gates.
// 256Mx128N tile, 512 thr / 8 waves, BK=32, THREE buffers, ONE barrier/tile,
// counted vmcnt(3) (tile s+1 loads stay in flight across the barrier = T4).
// Why 3 buffers removes the 2nd barrier: at tile s the prefetch target
// (s+2)%3 is the buffer whose readers finished BEFORE this tile's top
// barrier (their ds_reads complete pre-barrier; issue is post-barrier).
// Prefetch slack = 2 tiles (~2700cyc >> 900cyc HBM). + T5 setprio, 2-phase
// ds_read/MFMA interleave. 72 KB LDS -> 2 blocks/CU (16 waves).
// ---------------------------------------------------------------------------
template<int TAG, int KEYOUT>
__global__ __launch_bounds__(512) void k_gemm_bt(const u16* __restrict__ A,
                                                 const u16* __restrict__ B,
                                                 void* __restrict__ Cv,
                                                 int M, int N, int K,
                                                 const float* __restrict__ res) {
    __shared__ __align__(16) u16 As[3][8192];   // [cs(4)][row(256)][8]
    __shared__ __align__(16) u16 Bs[3][4096];   // [cs(4)][row(128)][8]
    int tid = threadIdx.x;
    int wave = tid >> 6, lane = tid & 63;
    int m0 = blockIdx.y * 256, n0 = blockIdx.x * 128;
    int wm = (wave >> 1) * 64, wn = (wave & 1) * 64;
    int kg = lane >> 4, l15 = lane & 15;

    // A chunks 2w,2w+1 ; B chunk w  (chunk: rb=row-block of 64, cs=col-slice of 8)
    int ca0 = wave * 2, ca1 = wave * 2 + 1;
    int a0rb = ca0 & 3, a0cs = ca0 >> 2;
    int a1rb = ca1 & 3, a1cs = ca1 >> 2;
    int brb = wave & 1, bcs = wave >> 1;
    const u16* gA0 = A + (size_t)(m0 + a0rb * 64 + lane) * K + a0cs * 8;
    const u16* gA1 = A + (size_t)(m0 + a1rb * 64 + lane) * K + a1cs * 8;
    const u16* gB0 = B + (size_t)(n0 + brb * 64 + lane) * K + bcs * 8;
    int sa0 = a0cs * 2048 + a0rb * 512;   // u16 offsets
    int sa1 = a1cs * 2048 + a1rb * 512;
    int sb0 = bcs * 1024 + brb * 512;

    f32x4 acc[4][4];
#pragma unroll
    for (int i = 0; i < 4; i++)
#pragma unroll
        for (int j = 0; j < 4; j++) { f32x4 z = {0.f, 0.f, 0.f, 0.f}; acc[i][j] = z; }

    const int nsteps = K >> 5;
    // prologue: stage tiles 0,1 (6 loads/wave outstanding)
#pragma unroll
    for (int p = 0; p < 2; p++) {
        int kk = p * 32;
        gload16(gA0 + kk, As[p] + sa0);
        gload16(gA1 + kk, As[p] + sa1);
        gload16(gB0 + kk, Bs[p] + sb0);
    }

    int cur = 0, nxt = 2;
    for (int s = 0; s < nsteps; s++) {
        // own tile-s loads retired (oldest 3); tile s+1's 3 stay in flight
        asm volatile("s_waitcnt vmcnt(3)" ::: "memory");
        __builtin_amdgcn_s_barrier();            // buf[cur] fully staged
        __builtin_amdgcn_sched_barrier(0);
        // issue tile s+2 into buf[nxt] (readers of nxt finished pre-barrier)
        {
            int tn = (s + 2 < nsteps) ? s + 2 : nsteps - 1;
            int kn = tn * 32;
            gload16(gA0 + kn, As[nxt] + sa0);
            gload16(gA1 + kn, As[nxt] + sa1);
            gload16(gB0 + kn, Bs[nxt] + sb0);
        }
        const u16* Ac = As[cur];
        const u16* Bc = Bs[cur];
        short8 af[4], bg0, bg1, bg2, bg3;
#pragma unroll
        for (int mi = 0; mi < 4; mi++) {
            int row = wm + mi * 16 + l15;
            af[mi] = *reinterpret_cast<const short8*>(&Ac[(kg * 256 + row) * 8]);
        }
        // phase A: ni = 0,1
        bg0 = *reinterpret_cast<const short8*>(&Bc[(kg * 128 + wn + 0 * 16 + l15) * 8]);
        bg1 = *reinterpret_cast<const short8*>(&Bc[(kg * 128 + wn + 1 * 16 + l15) * 8]);
        __builtin_amdgcn_s_setprio(1);
#pragma unroll
        for (int mi = 0; mi < 4; mi++) {
            acc[mi][0] = mfma_bf16(af[mi], bg0, acc[mi][0]);
            acc[mi][1] = mfma_bf16(af[mi], bg1, acc[mi][1]);
        }
        __builtin_amdgcn_s_setprio(0);
        // phase B: ni = 2,3
        bg2 = *reinterpret_cast<const short8*>(&Bc[(kg * 128 + wn + 2 * 16 + l15) * 8]);
        bg3 = *reinterpret_cast<const short8*>(&Bc[(kg * 128 + wn + 3 * 16 + l15) * 8]);
        __builtin_amdgcn_s_setprio(1);
#pragma unroll
        for (int mi = 0; mi < 4; mi++) {
            acc[mi][2] = mfma_bf16(af[mi], bg2, acc[mi][2]);
            acc[mi][3] = mfma_bf16(af[mi], bg3, acc[mi][3]);
        }
        __builtin_amdgcn_s_setprio(0);
        cur = (cur == 2) ? 0 : cur + 1;
        nxt = (nxt == 2) ? 0 : nxt + 1;
    }
    asm volatile("s_waitcnt vmcnt(0)" ::: "memory");   // drain tail duplicates
    asm volatile("s_nop 7\n\ts_nop 7");
#pragma unroll
    for (int mi = 0; mi < 4; mi++) {
#pragma unroll
        for (int ni = 0; ni < 4; ni++) {
            int col = n0 + wn + ni * 16 + l15;
#pragma unroll
            for (int r = 0; r < 4; r++) {
                int rowm = m0 + wm + mi * 16 + (lane >> 4) * 4 + r;
                size_t idx = (size_t)rowm * N + col;
                float v = acc[mi][ni][r];
                if (KEYOUT) {
                    ((u16*)Cv)[idx] = bfkey(f2bf(v));
                } else {
                    if (res) v += res[idx];
                    ((float*)Cv)[idx] = v;
                }
            }
        }
    }
}

// ---------------------------------------------------------------------------
// Fused top-k threshold gate + sparse emit.  keys row stride = ldk.
// Phase 1: 2-pass radix select over u16 keys (wave-level suffix scan, 2
//          barriers/pass) -> exact kth-largest; select keys >= thr;
//          wave 0 computes gate values + colsum atomics.
// Phase 2: gather-emit, 8 weight rows in flight (latency-bound phase).
// ---------------------------------------------------------------------------
template<int TWO, int RES>
__global__ __launch_bounds__(256) void k_gate_emit(const u16* __restrict__ keys_g, int ldk,
                                                   int NC, int ksel, int row_off,
                                                   const float* __restrict__ tau, int tau_stride, int tcol0,
                                                   const u16* __restrict__ w,
                                                   u16* __restrict__ OA, u16* __restrict__ OB,
                                                   float* __restrict__ io,
                                                   float* __restrict__ csA, float* __restrict__ csB) {
    extern __shared__ u16 keys[];
    __shared__ int   hist[256];
    __shared__ int   segsum[4];
    __shared__ int   scnt;
    __shared__ int   dsel;
    __shared__ int   knext;
    __shared__ int   sidx[CAPK];
    __shared__ float svA[CAPK];
    __shared__ float svB[CAPK];
    int r = blockIdx.x, tid = threadIdx.x, wave = tid >> 6, lane = tid & 63;
    int t = row_off + r;
    const int cap = TWO ? CAPA : (RES ? CAPK : CAPA);

    // stage keys (uint4 = 8 keys)
    const uint4* srow8 = reinterpret_cast<const uint4*>(keys_g + (size_t)r * ldk);
    for (int c = tid; c < NC / 8; c += 256)
        reinterpret_cast<uint4*>(keys)[c] = srow8[c];
    if (tid == 0) scnt = 0;

    // ---- radix select: 2 passes of 8 bits, MSB first ----
    u32 prefix = 0;
    int krem = ksel;
#pragma unroll
    for (int pass = 0; pass < 2; pass++) {
        int shift = 8 - pass * 8;
        hist[tid] = 0;
        __syncthreads();
        u32 pmask = (pass == 0) ? 0u : 0xFF00u;
        for (int i = tid; i < NC; i += 256) {
            u32 ky = keys[i];
            if ((ky & pmask) == prefix)
                atomicAdd(&hist[(ky >> shift) & 255], 1);
        }
        __syncthreads();
        // wave-level suffix scan: wave w owns bins w*64..w*64+63
        int v = hist[tid];
#pragma unroll
        for (int off = 1; off < 64; off <<= 1) {
            int o = __shfl_down(v, off);
            if (lane + off < 64) v += o;
        }
        if (lane == 0) segsum[wave] = v;   // total of this wave's 64 bins
        __syncthreads();
        int cross = 0;
#pragma unroll
        for (int w2 = 0; w2 < 4; w2++)
            if (w2 > wave) cross += segsum[w2];
        int sfx = v + cross;                                // suffix sum from bin tid
        int vnext = __shfl_down(v, 1);
        int sfx_next = (lane < 63) ? (vnext + cross) : cross;  // suffix from bin tid+1
        if (sfx >= krem && (tid == 255 || sfx_next < krem)) {
            dsel = tid;
            knext = krem - sfx_next;
        }
        __syncthreads();
        prefix |= ((u32)dsel) << shift;
        krem = knext;
        __syncthreads();
    }
    u32 thr = prefix;   // exact kth-largest u16 key

    // ---- select keys >= thr; store raw score (reuse svA slot) ----
    for (int i = tid; i < NC; i += 256) {
        u32 ky = keys[i];
        if (ky >= thr) {
            int p = atomicAdd(&scnt, 1);
            if (p < cap) {
                sidx[p] = i;
                svA[p] = bf2f(keybf((u16)ky));
            }
        }
    }
    __syncthreads();
    int n = scnt < cap ? scnt : cap;

    // ---- wave 0: gate values -> svA/svB (emit weights), colsum atomics ----
    if (wave == 0) {
        float tA = tau[(size_t)t * tau_stride + tcol0];
        float tB = TWO ? tau[(size_t)t * tau_stride + tcol0 + 1] : 0.f;
        float sumA = 0.f, mxA = -1e30f, sumB = 0.f, mxB = -1e30f;
        float sv0 = (lane < n) ? svA[lane] : 0.f;
        float sv1 = (lane + 64 < n) ? svA[lane + 64] : 0.f;
        for (int i = lane; i < n; i += 64) {
            float sv = svA[i];
            float rA = sv - tA;
            float gA = rA > 0.f ? rA : 1e-8f * expf(rA);
            float eA = expf(gA) - 1.0f;            // match reference quantization
            sumA += eA; mxA = fmaxf(mxA, eA);
            if (TWO) {
                float rB = sv - tB;
                float gB = rB > 0.f ? rB : 1e-8f * expf(rB);
                float eB = expf(gB) - 1.0f;
                sumB += eB; mxB = fmaxf(mxB, eB);
            }
        }
#pragma unroll
        for (int off = 32; off > 0; off >>= 1) {
            sumA += __shfl_xor(sumA, off); mxA = fmaxf(mxA, __shfl_xor(mxA, off));
            sumB += __shfl_xor(sumB, off); mxB = fmaxf(mxB, __shfl_xor(mxB, off));
        }
        float fA = tanhf(mxA) / (sumA + 1e-8f);
        float fB = tanhf(mxB) / (sumB + 1e-8f);
        // two strided slots max (n <= 96 < 128)
        if (lane < n) {
            float sv = sv0; int ci = sidx[lane];
            float rA = sv - tA;
            float gA = rA > 0.f ? rA : 1e-8f * expf(rA);
            float ga = (expf(gA) - 1.0f) * fA;
            svA[lane] = ga * sv;                   // emit weight = score * gate
            atomicAdd(&csA[ci], ga);
            if (TWO) {
                float rB = sv - tB;
                float gB = rB > 0.f ? rB : 1e-8f * expf(rB);
                float gb = (expf(gB) - 1.0f) * fB;
                svB[lane] = gb * sv;
                atomicAdd(&csB[ci], gb);
            }
        }
        if (lane + 64 < n) {
            float sv = sv1; int ci = sidx[lane + 64];
            float rA = sv - tA;
            float gA = rA > 0.f ? rA : 1e-8f * expf(rA);
            float ga = (expf(gA) - 1.0f) * fA;
            svA[lane + 64] = ga * sv;
            atomicAdd(&csA[ci], ga);
            if (TWO) {
                float rB = sv - tB;
                float gB = rB > 0.f ? rB : 1e-8f * expf(rB);
                float gb = (expf(gB) - 1.0f) * fB;
                svB[lane + 64] = gb * sv;
                atomicAdd(&csB[ci], gb);
            }
        }
    }
    __syncthreads();

    // ---- phase 2: gather-emit (all threads), 8 rows in flight ----
    float a0 = 0, a1 = 0, a2 = 0, a3 = 0, b0 = 0, b1 = 0, b2 = 0, b3 = 0;
    float4 base;
    if (RES) base = reinterpret_cast<const float4*>(io + (size_t)t * DIM)[tid];
    int s = 0;
    for (; s + 8 <= n; s += 8) {
        ushort4 wv[8];
#pragma unroll
        for (int j = 0; j < 8; j++)
            wv[j] = reinterpret_cast<const ushort4*>(w + (size_t)sidx[s + j] * DIM)[tid];
#pragma unroll
        for (int j = 0; j < 8; j++) {
            float va = svA[s + j];
            a0 += va * bf2f(wv[j].x); a1 += va * bf2f(wv[j].y);
            a2 += va * bf2f(wv[j].z); a3 += va * bf2f(wv[j].w);
            if (TWO) {
                float vb = svB[s + j];
                b0 += vb * bf2f(wv[j].x); b1 += vb * bf2f(wv[j].y);
                b2 += vb * bf2f(wv[j].z); b3 += vb * bf2f(wv[j].w);
            }
        }
    }
    for (; s < n; s++) {
        const ushort4 wv = reinterpret_cast<const ushort4*>(w + (size_t)sidx[s] * DIM)[tid];
        float va = svA[s];
        a0 += va * bf2f(wv.x); a1 += va * bf2f(wv.y); a2 += va * bf2f(wv.z); a3 += va * bf2f(wv.w);
        if (TWO) {
            float vb = svB[s];
            b0 += vb * bf2f(wv.x); b1 += vb * bf2f(wv.y); b2 += vb * bf2f(wv.z); b3 += vb * bf2f(wv.w);
        }
    }
    if (RES) {
        reinterpret_cast<float4*>(io + (size_t)t * DIM)[tid] =
            make_float4(base.x + a0, base.y + a1, base.z + a2, base.w + a3);
    } else {
        reinterpret_cast<ushort4*>(OA + (size_t)t * DIM)[tid] = make_ushort4(f2bf(a0), f2bf(a1), f2bf(a2), f2bf(a3));
        if (TWO)
            reinterpret_cast<ushort4*>(OB + (size_t)t * DIM)[tid] = make_ushort4(f2bf(b0), f2bf(b1), f2bf(b2), f2bf(b3));
    }
}

// ---------------------------------------------------------------------------
// Causal flash attention, bf16 MFMA (16x16x32).
// Block = 256 thr / 4 waves, one (b,h), 64 q rows (16 per wave).
// qt = gridDim.z-1-blockIdx.z: HEAVY q-tiles dispatch first (LPT), while the
// concurrent-resident set is still "all (h,bb) at one qt" -> K/V rows shared
// in L2 (round-6 lesson: dimension ORDER preserved, only z relabeled).
// ---------------------------------------------------------------------------
__global__ __launch_bounds__(256) void k_attn(const u16* __restrict__ Q,
                                              const u16* __restrict__ K,
                                              const u16* __restrict__ V,
                                              u16* __restrict__ O) {
    __shared__ __align__(16) u16 Ks[64 * APAD];
    __shared__ __align__(16) u16 Vt[64 * APAD];
    __shared__ __align__(16) u16 Ps[4][16 * APAD];
    int tid = threadIdx.x, wave = tid >> 6, lane = tid & 63;
    int h = blockIdx.x, bb = blockIdx.y;
    int qt = gridDim.z - 1 - blockIdx.z;   // heavy-first (z relabel only)
    int q0 = qt * 64;
    size_t base = ((size_t)bb * SLEN) * DIM + (size_t)h * DH;
    int sr = tid >> 2, sc = (tid & 3) * 16;     // staging row (0..63), col (0/16/32/48)
    int g = lane >> 4, l15 = lane & 15;

    // Q fragments direct from global (16 rows x 64B per quarter-wave, one-time)
    const u16* qrow = Q + base + (size_t)(q0 + wave * 16 + l15) * DIM;
    short8 qa0 = *reinterpret_cast<const short8*>(qrow + g * 8);
    short8 qa1 = *reinterpret_cast<const short8*>(qrow + 32 + g * 8);

    float m[4], l[4];
    f32x4 oacc[4];
#pragma unroll
    for (int i = 0; i < 4; i++) {
        m[i] = -1e30f; l[i] = 0.f;
        f32x4 z = {0.f, 0.f, 0.f, 0.f}; oacc[i] = z;
    }
    u16* pw = &Ps[wave][0];

    for (int kc = 0; kc <= qt; kc++) {
        __syncthreads();
        // ---- stage K [key][dim] and V transposed [dim][key] ----
        {
            const u16* kp = K + base + (size_t)(kc * 64 + sr) * DIM + sc;
            *reinterpret_cast<short8*>(&Ks[sr * APAD + sc])     = *reinterpret_cast<const short8*>(kp);
            *reinterpret_cast<short8*>(&Ks[sr * APAD + sc + 8]) = *reinterpret_cast<const short8*>(kp + 8);
            const u16* vp = V + base + (size_t)(kc * 64 + sr) * DIM + sc;
            short8 w0 = *reinterpret_cast<const short8*>(vp);
            short8 w1 = *reinterpret_cast<const short8*>(vp + 8);
            const u16* w0p = reinterpret_cast<const u16*>(&w0);
            const u16* w1p = reinterpret_cast<const u16*>(&w1);
#pragma unroll
            for (int j = 0; j < 16; j++) {
                int d = sc + j;
                int phys = (((sr >> 3) + d + (d >> 4)) & 7);   // rotate key-blocks per dim
                Vt[d * APAD + phys * 8 + (sr & 7)] = (j < 8) ? w0p[j] : w1p[j - 8];
            }
        }
        __syncthreads();

        // ---- QK^T: 8 MFMAs -> s4[ks] (q_local = wave*16 + g*4 + r, key = ks*16 + l15)
        f32x4 s4[4];
#pragma unroll
        for (int ks = 0; ks < 4; ks++) {
            f32x4 z = {0.f, 0.f, 0.f, 0.f}; s4[ks] = z;
            short8 kb0 = *reinterpret_cast<const short8*>(&Ks[(ks * 16 + l15) * APAD + g * 8]);
            short8 kb1 = *reinterpret_cast<const short8*>(&Ks[(ks * 16 + l15) * APAD + 32 + g * 8]);
            s4[ks] = mfma_bf16(qa0, kb0, s4[ks]);
            s4[ks] = mfma_bf16(qa1, kb1, s4[ks]);
        }
        asm volatile("s_nop 7\n\ts_nop 7");   // MFMA -> VALU read hazard

        // ---- scale + causal mask ----
        int key_base = kc * 64 + l15;
#pragma unroll
        for (int ks = 0; ks < 4; ks++) {
            int key = key_base + ks * 16;
#pragma unroll
            for (int r = 0; r < 4; r++) {
                int q_abs = q0 + wave * 16 + g * 4 + r;
                float sv = s4[ks][r] * 0.125f;
                s4[ks][r] = (key > q_abs) ? -1e30f : sv;
            }
        }

        // ---- online softmax per q-row; write P (bf16) to per-wave LDS ----
#pragma unroll
        for (int r = 0; r < 4; r++) {
            float mx = fmaxf(fmaxf(s4[0][r], s4[1][r]), fmaxf(s4[2][r], s4[3][r]));
            mx = fmaxf(mx, __shfl_xor(mx, 1));
            mx = fmaxf(mx, __shfl_xor(mx, 2));
            mx = fmaxf(mx, __shfl_xor(mx, 4));
            mx = fmaxf(mx, __shfl_xor(mx, 8));
            float mnew = fmaxf(m[r], mx);
            float al = __expf(m[r] - mnew);
            m[r] = mnew;
            float p0 = __expf(s4[0][r] - mnew);
            float p1 = __expf(s4[1][r] - mnew);
            float p2 = __expf(s4[2][r] - mnew);
            float p3 = __expf(s4[3][r] - mnew);
            float ps = p0 + p1 + p2 + p3;
            ps += __shfl_xor(ps, 1);
            ps += __shfl_xor(ps, 2);
            ps += __shfl_xor(ps, 4);
            ps += __shfl_xor(ps, 8);
            l[r] = l[r] * al + ps;
#pragma unroll
            for (int ds_ = 0; ds_ < 4; ds_++) oacc[ds_][r] *= al;
            int row = g * 4 + r;
            pw[row * APAD +  0 + l15] = f2bf(p0);
            pw[row * APAD + 16 + l15] = f2bf(p1);
            pw[row * APAD + 32 + l15] = f2bf(p2);
            pw[row * APAD + 48 + l15] = f2bf(p3);
        }

        // ---- PV: read P as A-fragments, V^T as B-fragments; 8 MFMAs ----
        short8 pa0 = *reinterpret_cast<const short8*>(&pw[l15 * APAD + g * 8]);
        short8 pa1 = *reinterpret_cast<const short8*>(&pw[l15 * APAD + 32 + g * 8]);
#pragma unroll
        for (int dsub = 0; dsub < 4; dsub++) {
            int d = dsub * 16 + l15;
            int rot = d + (d >> 4);
            short8 vb0 = *reinterpret_cast<const short8*>(&Vt[d * APAD + (((0 + g) + rot) & 7) * 8]);
            short8 vb1 = *reinterpret_cast<const short8*>(&Vt[d * APAD + (((4 + g) + rot) & 7) * 8]);
            oacc[dsub] = mfma_bf16(pa0, vb0, oacc[dsub]);
            oacc[dsub] = mfma_bf16(pa1, vb1, oacc[dsub]);
        }
    }
    asm volatile("s_nop 7\n\ts_nop 7");       // MFMA -> VALU read hazard

    // ---- epilogue: O = oacc / l, bf16 ----
#pragma unroll
    for (int r = 0; r < 4; r++) {
        float inv = 1.0f / l[r];
        int row = q0 + wave * 16 + g * 4 + r;
#pragma unroll
        for (int dsub = 0; dsub < 4; dsub++) {
            O[base + (size_t)row * DIM + dsub * 16 + l15] = f2bf(oacc[dsub][r] * inv);
        }
    }
}

// ---------------------------------------------------------------------------
// aux = sum over gate columns of (colsum/T - 1/N)^2 * N
// ---------------------------------------------------------------------------
__global__ __launch_bounds__(256) void k_aux(const float* __restrict__ cs,
                                             float* __restrict__ out_aux) {
    __shared__ float red[4];
    int gtid = blockIdx.x * 256 + threadIdx.x;
    float acc = 0.f;
    for (int i = gtid; i < 3 * 4096 + 8192; i += gridDim.x * 256) {
        float mean = cs[i] * (1.0f / 4096.0f);
        float tN, Nf;
        if (i < 12288) { tN = 1.0f / 4096.0f; Nf = 4096.0f; }
        else           { tN = 1.0f / 8192.0f; Nf = 8192.0f; }
        float d = mean - tN;
        acc += d * d * Nf;
    }
    acc = blockReduceF(acc, red, threadIdx.x >> 6, threadIdx.x & 63);
    if (threadIdx.x == 0) atomicAdd(out_aux, acc);
}

// ---------------------------------------------------------------------------
extern "C" void kernel_launch(void* const* d_in, const int* in_sizes, int n_in,
                              void* d_out, int out_size, void* d_ws, size_t ws_size,
                              hipStream_t stream) {
    const float* x         = (const float*)d_in[0];
    const float* qk_emb    = (const float*)d_in[1];
    const float* qk_w      = (const float*)d_in[2];
    const float* v_emb     = (const float*)d_in[3];
    const float* v_w       = (const float*)d_in[4];
    const float* know_emb  = (const float*)d_in[5];
    const float* know_w    = (const float*)d_in[6];
    const float* tau_attn_k = (const float*)d_in[7];
    const float* tau_attn_b = (const float*)d_in[8];
    const float* tau_know_k = (const float*)d_in[9];
    const float* tau_know_b = (const float*)d_in[10];
    const float* expand_O  = (const float*)d_in[11];
    const float* ln1_s     = (const float*)d_in[12];
    const float* ln1_b     = (const float*)d_in[13];
    const float* ln2_s     = (const float*)d_in[14];
    const float* ln2_b     = (const float*)d_in[15];
    float* out = (float*)d_out;
    char*  ws  = (char*)d_ws;

    // workspace layout (bytes). NOTE: qkemb_bf and vemb_bf MUST stay adjacent
    // (merged N=8192 score GEMM treats them as one [8192][1024] matrix).
    u16*   nrm_bf   = (u16*)(ws + 0);                 //  8 MB
    u16*   qkemb_bf = (u16*)(ws + 8388608);           //  8 MB
    u16*   vemb_bf  = (u16*)(ws + 16777216);          //  8 MB (contiguous after qkemb!)
    u16*   knemb_bf = (u16*)(ws + 25165824);          // 16 MB
    u16*   expT_bf  = (u16*)(ws + 41943040);          //  2 MB
    u16*   attn_bf  = (u16*)(ws + 44040192);          //  8 MB
    u16*   qkw_bf   = (u16*)(ws + 52428800);          //  8 MB
    u16*   vw_bf    = (u16*)(ws + 60817408);          //  8 MB
    u16*   knw_bf   = (u16*)(ws + 69206016);          // 16 MB
    u16*   Qb       = (u16*)(ws + 85983232);          //  8 MB (bf16)
    u16*   Kb       = (u16*)(ws + 94371840);          //  8 MB (bf16)
    u16*   Vb       = (u16*)(ws + 102760448);         //  8 MB (bf16)
    u16*   keysbuf  = (u16*)(ws + 111149056);         // 64 MB (u16 keys, [TOK][8192])
    float* tauA     = (float*)(ws + 185384960);       // [T][3]
    float* tauKn    = (float*)(ws + 185434112);       // [T]
    float* colsum   = (float*)(ws + 185450496);       // 20480 floats: Q,K,V,Kn
    const size_t WS_NEEDED = 185532416;
    if (ws_size < WS_NEEDED) return;   // workspace too small — bail cleanly

    float* colQ = colsum, *colK = colsum + 4096, *colV = colsum + 8192, *colKn = colsum + 12288;

    hipMemsetAsync(colsum, 0, 20480 * sizeof(float), stream);
    hipMemsetAsync(out + (size_t)TOK * DIM, 0, sizeof(float), stream);

    // bf16 conversions: all six tables in one launch + expand_O transpose
    k_convert_all<<<2048, 256, 0, stream>>>(qk_emb, v_emb, know_emb, qk_w, v_w, know_w,
                                            qkemb_bf, vemb_bf, knemb_bf, qkw_bf, vw_bf, knw_bf);
    k_transpose_bf16<<<dim3(32, 32), 256, 0, stream>>>(expand_O, expT_bf);

    // LN1 + tau(3)
    k_ln_tau<<<TOK, 256, 0, stream>>>(x, ln1_s, ln1_b, tau_attn_k, tau_attn_b, 3, nrm_bf, tauA);

    // merged scores [qk | v] (u16 keys, N=8192): B = qkemb_bf ++ vemb_bf
    k_gemm_bt<0, 1><<<dim3(8192 / 128, TOK / 256), 512, 0, stream>>>(nrm_bf, qkemb_bf, keysbuf, TOK, 8192, DIM, nullptr);
    // fused gate+emit Q,K (cols 0..4095 of merged keys)
    k_gate_emit<1, 0><<<TOK, 256, NQK * sizeof(u16), stream>>>(keysbuf, 8192, NQK, 32, 0, tauA, 3, 0,
                                                               qkw_bf, Qb, Kb, nullptr, colQ, colK);
    // fused gate+emit V (cols 4096..8191)
    k_gate_emit<0, 0><<<TOK, 256, NV * sizeof(u16), stream>>>(keysbuf + 4096, 8192, NV, 32, 0, tauA, 3, 2,
                                                              vw_bf, Vb, nullptr, nullptr, colV, nullptr);

    // causal MHA (bf16 MFMA) -> bf16  (heavy q-tiles first via z relabel)
    k_attn<<<dim3(NH, 2, SLEN / 64), 256, 0, stream>>>(Qb, Kb, Vb, attn_bf);

    // out @ expand_O + residual x  -> x1 (stored in d_out)
    k_gemm_bt<2, 0><<<dim3(DIM / 128, TOK / 256), 512, 0, stream>>>(attn_bf, expT_bf, out, TOK, DIM, DIM, x);

    // LN2 + tau_know
    k_ln_tau<<<TOK, 256, 0, stream>>>(out, ln2_s, ln2_b, tau_know_k, tau_know_b, 1, nrm_bf, tauKn);

    // know scores (u16 keys) + fused gate+emit(+residual), full M in one shot
    k_gemm_bt<3, 1><<<dim3(NKN / 128, TOK / 256), 512, 0, stream>>>(nrm_bf, knemb_bf, keysbuf, TOK, NKN, DIM, nullptr);
    k_gate_emit<0, 1><<<TOK, 256, NKN * sizeof(u16), stream>>>(keysbuf, NKN, NKN, 64, 0, tauKn, 1, 0,
                                                               knw_bf, nullptr, nullptr, out, colKn, nullptr);

    // aux scalar
    k_aux<<<20, 256, 0, stream>>>(colsum, out + (size_t)TOK * DIM);
}

// Round 17
// 691.127 us; speedup vs baseline: 1.0229x; 1.0229x over previous
//
#include <hip/hip_runtime.h>

// ---------------------------------------------------------------------------
// Problem constants (fixed by the reference)
// ---------------------------------------------------------------------------
#define TOK   4096      // B*S
#define DIM   1024
#define NQK   4096
#define NV    4096
#define NKN   8192
#define SLEN  2048
#define NH    16
#define DH    64
#define CAPA  48        // capacity for k=32 gates (slack for ties)
#define CAPK  96        // capacity for k=64 gate
#define APAD  72        // attn LDS row pad (bf16 elems): 144B keeps b128 align

typedef float  f32x4  __attribute__((ext_vector_type(4)));
typedef short  short8 __attribute__((ext_vector_type(8)));
typedef unsigned int  u32;
typedef unsigned short u16;

__device__ __forceinline__ u16 f2bf(float f) {
    u32 u = __float_as_uint(f);
    u32 r = (u + 0x7fffu + ((u >> 16) & 1u)) >> 16;
    return (u16)r;
}
__device__ __forceinline__ float bf2f(u16 v) { return __uint_as_float(((u32)v) << 16); }

// monotone bf16 -> u16 key (order-preserving over floats)
__device__ __forceinline__ u16 bfkey(u16 b) {
    return (b & 0x8000u) ? (u16)(~b) : (u16)(b | 0x8000u);
}
// inverse: key -> bf16 bits
__device__ __forceinline__ u16 keybf(u16 k) {
    return (k & 0x8000u) ? (u16)(k & 0x7fffu) : (u16)(~k);
}

__device__ __forceinline__ f32x4 mfma_bf16(short8 a, short8 b, f32x4 c) {
    asm volatile("v_mfma_f32_16x16x32_bf16 %0, %1, %2, %0"
                 : "+v"(c) : "v"(a), "v"(b));
    return c;
}

// async global->LDS, 16B per lane; LDS dest = wave-uniform base + lane*16
__device__ __forceinline__ void gload16(const u16* g, u16* s) {
    __builtin_amdgcn_global_load_lds((const __attribute__((address_space(1))) void*)g,
                                     (__attribute__((address_space(3))) void*)s, 16, 0, 0);
}

__device__ __forceinline__ float blockReduceF(float v, float* red, int wave, int lane) {
#pragma unroll
    for (int off = 32; off > 0; off >>= 1) v += __shfl_xor(v, off);
    __syncthreads();
    if (lane == 0) red[wave] = v;
    __syncthreads();
    return red[0] + red[1] + red[2] + red[3];
}

// ---------------------------------------------------------------------------
// fused f32 -> bf16 conversion of all six tables (one launch)
// ---------------------------------------------------------------------------
__global__ __launch_bounds__(256) void k_convert_all(const float* __restrict__ p0,
                                                     const float* __restrict__ p1,
                                                     const float* __restrict__ p2,
                                                     const float* __restrict__ p3,
                                                     const float* __restrict__ p4,
                                                     const float* __restrict__ p5,
                                                     u16* __restrict__ o0, u16* __restrict__ o1,
                                                     u16* __restrict__ o2, u16* __restrict__ o3,
                                                     u16* __restrict__ o4, u16* __restrict__ o5) {
    const int S0 = 1048576, S1 = 2097152, S2 = 4194304, S3 = 5242880, S4 = 6291456, S5 = 8388608;
    for (int i = blockIdx.x * 256 + threadIdx.x; i < S5; i += gridDim.x * 256) {
        const float* in; u16* out; int off;
        if (i < S0)      { in = p0; out = o0; off = i; }
        else if (i < S1) { in = p1; out = o1; off = i - S0; }
        else if (i < S2) { in = p2; out = o2; off = i - S1; }
        else if (i < S3) { in = p3; out = o3; off = i - S2; }
        else if (i < S4) { in = p4; out = o4; off = i - S3; }
        else             { in = p5; out = o5; off = i - S4; }
        float4 v = reinterpret_cast<const float4*>(in)[off];
        reinterpret_cast<ushort4*>(out)[off] = make_ushort4(f2bf(v.x), f2bf(v.y), f2bf(v.z), f2bf(v.w));
    }
}

// transpose 1024x1024 f32 -> bf16 (out[n][k] = in[k][n])
__global__ __launch_bounds__(256) void k_transpose_bf16(const float* __restrict__ in,
                                                        u16* __restrict__ out) {
    __shared__ float tile[32][33];
    int bx = blockIdx.x * 32;   // col of in
    int by = blockIdx.y * 32;   // row of in
    int tx = threadIdx.x & 31;
    int ty = threadIdx.x >> 5;  // 0..7
    for (int r = ty; r < 32; r += 8)
        tile[r][tx] = in[(size_t)(by + r) * DIM + bx + tx];
    __syncthreads();
    for (int r = ty; r < 32; r += 8)
        out[(size_t)(bx + r) * DIM + by + tx] = f2bf(tile[tx][r]);
}

// ---------------------------------------------------------------------------
// LayerNorm + tau projection; writes bf16 normed + f32 tau[t][ntau]
// ---------------------------------------------------------------------------
__global__ __launch_bounds__(256) void k_ln_tau(const float* __restrict__ x,
                                                const float* __restrict__ sc,
                                                const float* __restrict__ bi,
                                                const float* __restrict__ tauk,
                                                const float* __restrict__ taub,
                                                int ntau,
                                                u16* __restrict__ nrm,
                                                float* __restrict__ tau_out) {
    __shared__ float red[4];
    int t = blockIdx.x, tid = threadIdx.x, wave = tid >> 6, lane = tid & 63;
    const float4 xv = reinterpret_cast<const float4*>(x + (size_t)t * DIM)[tid];
    float s = xv.x + xv.y + xv.z + xv.w;
    s = blockReduceF(s, red, wave, lane);
    float mean = s * (1.0f / DIM);
    float d0 = xv.x - mean, d1 = xv.y - mean, d2 = xv.z - mean, d3 = xv.w - mean;
    float ss = d0 * d0 + d1 * d1 + d2 * d2 + d3 * d3;
    ss = blockReduceF(ss, red, wave, lane);
    float rstd = rsqrtf(ss * (1.0f / DIM) + 1e-6f);
    const float4 scv = reinterpret_cast<const float4*>(sc)[tid];
    const float4 biv = reinterpret_cast<const float4*>(bi)[tid];
    float n0 = d0 * rstd * scv.x + biv.x;
    float n1 = d1 * rstd * scv.y + biv.y;
    float n2 = d2 * rstd * scv.z + biv.z;
    float n3 = d3 * rstd * scv.w + biv.w;
    ushort4 o = make_ushort4(f2bf(n0), f2bf(n1), f2bf(n2), f2bf(n3));
    reinterpret_cast<ushort4*>(nrm + (size_t)t * DIM)[tid] = o;
    int d = tid * 4;
    for (int j = 0; j < ntau; j++) {
        float p = n0 * tauk[(size_t)(d + 0) * ntau + j] + n1 * tauk[(size_t)(d + 1) * ntau + j]
                + n2 * tauk[(size_t)(d + 2) * ntau + j] + n3 * tauk[(size_t)(d + 3) * ntau + j];
        p = blockReduceF(p, red, wave, lane);
        if (tid == 0) tau_out[(size_t)t * ntau + j] = p + taub[j];
    }
}

// ---------------------------------------------------------------------------
// C = A[M][K] @ B[N][K]^T  (bf16 in).  KEYOUT=0: f32 out (+res fuse).
// KEYOUT=1: write u16 monotone keys of bf16(score) for radix-select gates.
// 256Mx128N tile, 512 threads / 8 waves (4M x 2N), BK=32, dbuf.
// FINAL FORM (round 15 = best measured, ~510 TF). Falsified alternatives:
// BK=64, 3-buf counted-vmcnt (x3 configs), reg-direct, XCD/supertile swizzle,
// 128^2 tile — all null or negative (rounds 8-16). The top-of-loop stall is
// structural for this template family at K=1024.
// ---------------------------------------------------------------------------
template<int TAG, int KEYOUT>
__global__ __launch_bounds__(512) void k_gemm_bt(const u16* __restrict__ A,
                                                 const u16* __restrict__ B,
                                                 void* __restrict__ Cv,
                                                 int M, int N, int K,
                                                 const float* __restrict__ res) {
    __shared__ __align__(16) u16 As[2][8192];   // [cs(4)][row(256)][8]
    __shared__ __align__(16) u16 Bs[2][4096];   // [cs(4)][row(128)][8]
    int tid = threadIdx.x;
    int wave = tid >> 6, lane = tid & 63;
    int m0 = blockIdx.y * 256, n0 = blockIdx.x * 128;
    int wm = (wave >> 1) * 64, wn = (wave & 1) * 64;
    int kg = lane >> 4, l15 = lane & 15;

    // A chunks 2w,2w+1 ; B chunk w  (chunk: rb=row-block of 64, cs=col-slice of 8)
    int ca0 = wave * 2, ca1 = wave * 2 + 1;
    int a0rb = ca0 & 3, a0cs = ca0 >> 2;
    int a1rb = ca1 & 3, a1cs = ca1 >> 2;
    int brb = wave & 1, bcs = wave >> 1;
    const u16* gA0 = A + (size_t)(m0 + a0rb * 64 + lane) * K + a0cs * 8;
    const u16* gA1 = A + (size_t)(m0 + a1rb * 64 + lane) * K + a1cs * 8;
    const u16* gB0 = B + (size_t)(n0 + brb * 64 + lane) * K + bcs * 8;
    int sa0 = a0cs * 2048 + a0rb * 512;   // u16 offsets
    int sa1 = a1cs * 2048 + a1rb * 512;
    int sb0 = bcs * 1024 + brb * 512;

    f32x4 acc[4][4];
#pragma unroll
    for (int i = 0; i < 4; i++)
#pragma unroll
        for (int j = 0; j < 4; j++) { f32x4 z = {0.f, 0.f, 0.f, 0.f}; acc[i][j] = z; }

    // prologue: stage tile 0 into buffer 0
    gload16(gA0, As[0] + sa0);
    gload16(gA1, As[0] + sa1);
    gload16(gB0, Bs[0] + sb0);

    int cur = 0;
    for (int k0 = 0; k0 < K; k0 += 32) {
        __syncthreads();   // buf[cur] staged & previous reads done
        if (k0 + 32 < K) { // stage next tile into buf[cur^1]; overlaps compute
            int kn = k0 + 32;
            gload16(gA0 + kn, As[cur ^ 1] + sa0);
            gload16(gA1 + kn, As[cur ^ 1] + sa1);
            gload16(gB0 + kn, Bs[cur ^ 1] + sb0);
        }
        const u16* Ac = As[cur];
        const u16* Bc = Bs[cur];
        short8 af[4], bg[4];
#pragma unroll
        for (int mi = 0; mi < 4; mi++) {
            int row = wm + mi * 16 + l15;
            af[mi] = *reinterpret_cast<const short8*>(&Ac[(kg * 256 + row) * 8]);
        }
#pragma unroll
        for (int ni = 0; ni < 4; ni++) {
            int row = wn + ni * 16 + l15;
            bg[ni] = *reinterpret_cast<const short8*>(&Bc[(kg * 128 + row) * 8]);
        }
#pragma unroll
        for (int mi = 0; mi < 4; mi++)
#pragma unroll
            for (int ni = 0; ni < 4; ni++)
                acc[mi][ni] = mfma_bf16(af[mi], bg[ni], acc[mi][ni]);
        cur ^= 1;
    }
    asm volatile("s_nop 7\n\ts_nop 7");
#pragma unroll
    for (int mi = 0; mi < 4; mi++) {
#pragma unroll
        for (int ni = 0; ni < 4; ni++) {
            int col = n0 + wn + ni * 16 + l15;
#pragma unroll
            for (int r = 0; r < 4; r++) {
                int rowm = m0 + wm + mi * 16 + (lane >> 4) * 4 + r;
                size_t idx = (size_t)rowm * N + col;
                float v = acc[mi][ni][r];
                if (KEYOUT) {
                    ((u16*)Cv)[idx] = bfkey(f2bf(v));
                } else {
                    if (res) v += res[idx];
                    ((float*)Cv)[idx] = v;
                }
            }
        }
    }
}

// ---------------------------------------------------------------------------
// Fused top-k threshold gate + sparse emit.  keys row stride = ldk.
// Phase 1: 2-pass radix select over u16 keys (wave-level suffix scan, 2
//          barriers/pass) -> exact kth-largest; select keys >= thr;
//          wave 0 computes gate values + colsum atomics.
// Phase 2: gather-emit, 8 weight rows in flight (latency-bound phase).
// ---------------------------------------------------------------------------
template<int TWO, int RES>
__global__ __launch_bounds__(256) void k_gate_emit(const u16* __restrict__ keys_g, int ldk,
                                                   int NC, int ksel, int row_off,
                                                   const float* __restrict__ tau, int tau_stride, int tcol0,
                                                   const u16* __restrict__ w,
                                                   u16* __restrict__ OA, u16* __restrict__ OB,
                                                   float* __restrict__ io,
                                                   float* __restrict__ csA, float* __restrict__ csB) {
    extern __shared__ u16 keys[];
    __shared__ int   hist[256];
    __shared__ int   segsum[4];
    __shared__ int   scnt;
    __shared__ int   dsel;
    __shared__ int   knext;
    __shared__ int   sidx[CAPK];
    __shared__ float svA[CAPK];
    __shared__ float svB[CAPK];
    int r = blockIdx.x, tid = threadIdx.x, wave = tid >> 6, lane = tid & 63;
    int t = row_off + r;
    const int cap = TWO ? CAPA : (RES ? CAPK : CAPA);

    // stage keys (uint4 = 8 keys)
    const uint4* srow8 = reinterpret_cast<const uint4*>(keys_g + (size_t)r * ldk);
    for (int c = tid; c < NC / 8; c += 256)
        reinterpret_cast<uint4*>(keys)[c] = srow8[c];
    if (tid == 0) scnt = 0;

    // ---- radix select: 2 passes of 8 bits, MSB first ----
    u32 prefix = 0;
    int krem = ksel;
#pragma unroll
    for (int pass = 0; pass < 2; pass++) {
        int shift = 8 - pass * 8;
        hist[tid] = 0;
        __syncthreads();
        u32 pmask = (pass == 0) ? 0u : 0xFF00u;
        for (int i = tid; i < NC; i += 256) {
            u32 ky = keys[i];
            if ((ky & pmask) == prefix)
                atomicAdd(&hist[(ky >> shift) & 255], 1);
        }
        __syncthreads();
        // wave-level suffix scan: wave w owns bins w*64..w*64+63
        int v = hist[tid];
#pragma unroll
        for (int off = 1; off < 64; off <<= 1) {
            int o = __shfl_down(v, off);
            if (lane + off < 64) v += o;
        }
        if (lane == 0) segsum[wave] = v;   // total of this wave's 64 bins
        __syncthreads();
        int cross = 0;
#pragma unroll
        for (int w2 = 0; w2 < 4; w2++)
            if (w2 > wave) cross += segsum[w2];
        int sfx = v + cross;                                // suffix sum from bin tid
        int vnext = __shfl_down(v, 1);
        int sfx_next = (lane < 63) ? (vnext + cross) : cross;  // suffix from bin tid+1
        if (sfx >= krem && (tid == 255 || sfx_next < krem)) {
            dsel = tid;
            knext = krem - sfx_next;
        }
        __syncthreads();
        prefix |= ((u32)dsel) << shift;
        krem = knext;
        __syncthreads();
    }
    u32 thr = prefix;   // exact kth-largest u16 key

    // ---- select keys >= thr; store raw score (reuse svA slot) ----
    for (int i = tid; i < NC; i += 256) {
        u32 ky = keys[i];
        if (ky >= thr) {
            int p = atomicAdd(&scnt, 1);
            if (p < cap) {
                sidx[p] = i;
                svA[p] = bf2f(keybf((u16)ky));
            }
        }
    }
    __syncthreads();
    int n = scnt < cap ? scnt : cap;

    // ---- wave 0: gate values -> svA/svB (emit weights), colsum atomics ----
    if (wave == 0) {
        float tA = tau[(size_t)t * tau_stride + tcol0];
        float tB = TWO ? tau[(size_t)t * tau_stride + tcol0 + 1] : 0.f;
        float sumA = 0.f, mxA = -1e30f, sumB = 0.f, mxB = -1e30f;
        float sv0 = (lane < n) ? svA[lane] : 0.f;
        float sv1 = (lane + 64 < n) ? svA[lane + 64] : 0.f;
        for (int i = lane; i < n; i += 64) {
            float sv = svA[i];
            float rA = sv - tA;
            float gA = rA > 0.f ? rA : 1e-8f * expf(rA);
            float eA = expf(gA) - 1.0f;            // match reference quantization
            sumA += eA; mxA = fmaxf(mxA, eA);
            if (TWO) {
                float rB = sv - tB;
                float gB = rB > 0.f ? rB : 1e-8f * expf(rB);
                float eB = expf(gB) - 1.0f;
                sumB += eB; mxB = fmaxf(mxB, eB);
            }
        }
#pragma unroll
        for (int off = 32; off > 0; off >>= 1) {
            sumA += __shfl_xor(sumA, off); mxA = fmaxf(mxA, __shfl_xor(mxA, off));
            sumB += __shfl_xor(sumB, off); mxB = fmaxf(mxB, __shfl_xor(mxB, off));
        }
        float fA = tanhf(mxA) / (sumA + 1e-8f);
        float fB = tanhf(mxB) / (sumB + 1e-8f);
        // two strided slots max (n <= 96 < 128)
        if (lane < n) {
            float sv = sv0; int ci = sidx[lane];
            float rA = sv - tA;
            float gA = rA > 0.f ? rA : 1e-8f * expf(rA);
            float ga = (expf(gA) - 1.0f) * fA;
            svA[lane] = ga * sv;                   // emit weight = score * gate
            atomicAdd(&csA[ci], ga);
            if (TWO) {
                float rB = sv - tB;
                float gB = rB > 0.f ? rB : 1e-8f * expf(rB);
                float gb = (expf(gB) - 1.0f) * fB;
                svB[lane] = gb * sv;
                atomicAdd(&csB[ci], gb);
            }
        }
        if (lane + 64 < n) {
            float sv = sv1; int ci = sidx[lane + 64];
            float rA = sv - tA;
            float gA = rA > 0.f ? rA : 1e-8f * expf(rA);
            float ga = (expf(gA) - 1.0f) * fA;
            svA[lane + 64] = ga * sv;
            atomicAdd(&csA[ci], ga);
            if (TWO) {
                float rB = sv - tB;
                float gB = rB > 0.f ? rB : 1e-8f * expf(rB);
                float gb = (expf(gB) - 1.0f) * fB;
                svB[lane + 64] = gb * sv;
                atomicAdd(&csB[ci], gb);
            }
        }
    }
    __syncthreads();

    // ---- phase 2: gather-emit (all threads), 8 rows in flight ----
    float a0 = 0, a1 = 0, a2 = 0, a3 = 0, b0 = 0, b1 = 0, b2 = 0, b3 = 0;
    float4 base;
    if (RES) base = reinterpret_cast<const float4*>(io + (size_t)t * DIM)[tid];
    int s = 0;
    for (; s + 8 <= n; s += 8) {
        ushort4 wv[8];
#pragma unroll
        for (int j = 0; j < 8; j++)
            wv[j] = reinterpret_cast<const ushort4*>(w + (size_t)sidx[s + j] * DIM)[tid];
#pragma unroll
        for (int j = 0; j < 8; j++) {
            float va = svA[s + j];
            a0 += va * bf2f(wv[j].x); a1 += va * bf2f(wv[j].y);
            a2 += va * bf2f(wv[j].z); a3 += va * bf2f(wv[j].w);
            if (TWO) {
                float vb = svB[s + j];
                b0 += vb * bf2f(wv[j].x); b1 += vb * bf2f(wv[j].y);
                b2 += vb * bf2f(wv[j].z); b3 += vb * bf2f(wv[j].w);
            }
        }
    }
    for (; s < n; s++) {
        const ushort4 wv = reinterpret_cast<const ushort4*>(w + (size_t)sidx[s] * DIM)[tid];
        float va = svA[s];
        a0 += va * bf2f(wv.x); a1 += va * bf2f(wv.y); a2 += va * bf2f(wv.z); a3 += va * bf2f(wv.w);
        if (TWO) {
            float vb = svB[s];
            b0 += vb * bf2f(wv.x); b1 += vb * bf2f(wv.y); b2 += vb * bf2f(wv.z); b3 += vb * bf2f(wv.w);
        }
    }
    if (RES) {
        reinterpret_cast<float4*>(io + (size_t)t * DIM)[tid] =
            make_float4(base.x + a0, base.y + a1, base.z + a2, base.w + a3);
    } else {
        reinterpret_cast<ushort4*>(OA + (size_t)t * DIM)[tid] = make_ushort4(f2bf(a0), f2bf(a1), f2bf(a2), f2bf(a3));
        if (TWO)
            reinterpret_cast<ushort4*>(OB + (size_t)t * DIM)[tid] = make_ushort4(f2bf(b0), f2bf(b1), f2bf(b2), f2bf(b3));
    }
}

// ---------------------------------------------------------------------------
// Causal flash attention, bf16 MFMA (16x16x32).
// Block = 256 thr / 4 waves, one (b,h), 64 q rows (16 per wave).
// qt = gridDim.z-1-blockIdx.z: HEAVY q-tiles dispatch first (LPT), while the
// concurrent-resident set is still "all (h,bb) at one qt" -> K/V rows shared
// in L2 (round-6 lesson: dimension ORDER preserved, only z relabeled).
// ---------------------------------------------------------------------------
__global__ __launch_bounds__(256) void k_attn(const u16* __restrict__ Q,
                                              const u16* __restrict__ K,
                                              const u16* __restrict__ V,
                                              u16* __restrict__ O) {
    __shared__ __align__(16) u16 Ks[64 * APAD];
    __shared__ __align__(16) u16 Vt[64 * APAD];
    __shared__ __align__(16) u16 Ps[4][16 * APAD];
    int tid = threadIdx.x, wave = tid >> 6, lane = tid & 63;
    int h = blockIdx.x, bb = blockIdx.y;
    int qt = gridDim.z - 1 - blockIdx.z;   // heavy-first (z relabel only)
    int q0 = qt * 64;
    size_t base = ((size_t)bb * SLEN) * DIM + (size_t)h * DH;
    int sr = tid >> 2, sc = (tid & 3) * 16;     // staging row (0..63), col (0/16/32/48)
    int g = lane >> 4, l15 = lane & 15;

    // Q fragments direct from global (16 rows x 64B per quarter-wave, one-time)
    const u16* qrow = Q + base + (size_t)(q0 + wave * 16 + l15) * DIM;
    short8 qa0 = *reinterpret_cast<const short8*>(qrow + g * 8);
    short8 qa1 = *reinterpret_cast<const short8*>(qrow + 32 + g * 8);

    float m[4], l[4];
    f32x4 oacc[4];
#pragma unroll
    for (int i = 0; i < 4; i++) {
        m[i] = -1e30f; l[i] = 0.f;
        f32x4 z = {0.f, 0.f, 0.f, 0.f}; oacc[i] = z;
    }
    u16* pw = &Ps[wave][0];

    for (int kc = 0; kc <= qt; kc++) {
        __syncthreads();
        // ---- stage K [key][dim] and V transposed [dim][key] ----
        {
            const u16* kp = K + base + (size_t)(kc * 64 + sr) * DIM + sc;
            *reinterpret_cast<short8*>(&Ks[sr * APAD + sc])     = *reinterpret_cast<const short8*>(kp);
            *reinterpret_cast<short8*>(&Ks[sr * APAD + sc + 8]) = *reinterpret_cast<const short8*>(kp + 8);
            const u16* vp = V + base + (size_t)(kc * 64 + sr) * DIM + sc;
            short8 w0 = *reinterpret_cast<const short8*>(vp);
            short8 w1 = *reinterpret_cast<const short8*>(vp + 8);
            const u16* w0p = reinterpret_cast<const u16*>(&w0);
            const u16* w1p = reinterpret_cast<const u16*>(&w1);
#pragma unroll
            for (int j = 0; j < 16; j++) {
                int d = sc + j;
                int phys = (((sr >> 3) + d + (d >> 4)) & 7);   // rotate key-blocks per dim
                Vt[d * APAD + phys * 8 + (sr & 7)] = (j < 8) ? w0p[j] : w1p[j - 8];
            }
        }
        __syncthreads();

        // ---- QK^T: 8 MFMAs -> s4[ks] (q_local = wave*16 + g*4 + r, key = ks*16 + l15)
        f32x4 s4[4];
#pragma unroll
        for (int ks = 0; ks < 4; ks++) {
            f32x4 z = {0.f, 0.f, 0.f, 0.f}; s4[ks] = z;
            short8 kb0 = *reinterpret_cast<const short8*>(&Ks[(ks * 16 + l15) * APAD + g * 8]);
            short8 kb1 = *reinterpret_cast<const short8*>(&Ks[(ks * 16 + l15) * APAD + 32 + g * 8]);
            s4[ks] = mfma_bf16(qa0, kb0, s4[ks]);
            s4[ks] = mfma_bf16(qa1, kb1, s4[ks]);
        }
        asm volatile("s_nop 7\n\ts_nop 7");   // MFMA -> VALU read hazard

        // ---- scale + causal mask ----
        int key_base = kc * 64 + l15;
#pragma unroll
        for (int ks = 0; ks < 4; ks++) {
            int key = key_base + ks * 16;
#pragma unroll
            for (int r = 0; r < 4; r++) {
                int q_abs = q0 + wave * 16 + g * 4 + r;
                float sv = s4[ks][r] * 0.125f;
                s4[ks][r] = (key > q_abs) ? -1e30f : sv;
            }
        }

        // ---- online softmax per q-row; write P (bf16) to per-wave LDS ----
#pragma unroll
        for (int r = 0; r < 4; r++) {
            float mx = fmaxf(fmaxf(s4[0][r], s4[1][r]), fmaxf(s4[2][r], s4[3][r]));
            mx = fmaxf(mx, __shfl_xor(mx, 1));
            mx = fmaxf(mx, __shfl_xor(mx, 2));
            mx = fmaxf(mx, __shfl_xor(mx, 4));
            mx = fmaxf(mx, __shfl_xor(mx, 8));
            float mnew = fmaxf(m[r], mx);
            float al = __expf(m[r] - mnew);
            m[r] = mnew;
            float p0 = __expf(s4[0][r] - mnew);
            float p1 = __expf(s4[1][r] - mnew);
            float p2 = __expf(s4[2][r] - mnew);
            float p3 = __expf(s4[3][r] - mnew);
            float ps = p0 + p1 + p2 + p3;
            ps += __shfl_xor(ps, 1);
            ps += __shfl_xor(ps, 2);
            ps += __shfl_xor(ps, 4);
            ps += __shfl_xor(ps, 8);
            l[r] = l[r] * al + ps;
#pragma unroll
            for (int ds_ = 0; ds_ < 4; ds_++) oacc[ds_][r] *= al;
            int row = g * 4 + r;
            pw[row * APAD +  0 + l15] = f2bf(p0);
            pw[row * APAD + 16 + l15] = f2bf(p1);
            pw[row * APAD + 32 + l15] = f2bf(p2);
            pw[row * APAD + 48 + l15] = f2bf(p3);
        }

        // ---- PV: read P as A-fragments, V^T as B-fragments; 8 MFMAs ----
        short8 pa0 = *reinterpret_cast<const short8*>(&pw[l15 * APAD + g * 8]);
        short8 pa1 = *reinterpret_cast<const short8*>(&pw[l15 * APAD + 32 + g * 8]);
#pragma unroll
        for (int dsub = 0; dsub < 4; dsub++) {
            int d = dsub * 16 + l15;
            int rot = d + (d >> 4);
            short8 vb0 = *reinterpret_cast<const short8*>(&Vt[d * APAD + (((0 + g) + rot) & 7) * 8]);
            short8 vb1 = *reinterpret_cast<const short8*>(&Vt[d * APAD + (((4 + g) + rot) & 7) * 8]);
            oacc[dsub] = mfma_bf16(pa0, vb0, oacc[dsub]);
            oacc[dsub] = mfma_bf16(pa1, vb1, oacc[dsub]);
        }
    }
    asm volatile("s_nop 7\n\ts_nop 7");       // MFMA -> VALU read hazard

    // ---- epilogue: O = oacc / l, bf16 ----
#pragma unroll
    for (int r = 0; r < 4; r++) {
        float inv = 1.0f / l[r];
        int row = q0 + wave * 16 + g * 4 + r;
#pragma unroll
        for (int dsub = 0; dsub < 4; dsub++) {
            O[base + (size_t)row * DIM + dsub * 16 + l15] = f2bf(oacc[dsub][r] * inv);
        }
    }
}

// ---------------------------------------------------------------------------
// aux = sum over gate columns of (colsum/T - 1/N)^2 * N
// ---------------------------------------------------------------------------
__global__ __launch_bounds__(256) void k_aux(const float* __restrict__ cs,
                                             float* __restrict__ out_aux) {
    __shared__ float red[4];
    int gtid = blockIdx.x * 256 + threadIdx.x;
    float acc = 0.f;
    for (int i = gtid; i < 3 * 4096 + 8192; i += gridDim.x * 256) {
        float mean = cs[i] * (1.0f / 4096.0f);
        float tN, Nf;
        if (i < 12288) { tN = 1.0f / 4096.0f; Nf = 4096.0f; }
        else           { tN = 1.0f / 8192.0f; Nf = 8192.0f; }
        float d = mean - tN;
        acc += d * d * Nf;
    }
    acc = blockReduceF(acc, red, threadIdx.x >> 6, threadIdx.x & 63);
    if (threadIdx.x == 0) atomicAdd(out_aux, acc);
}

// ---------------------------------------------------------------------------
extern "C" void kernel_launch(void* const* d_in, const int* in_sizes, int n_in,
                              void* d_out, int out_size, void* d_ws, size_t ws_size,
                              hipStream_t stream) {
    const float* x         = (const float*)d_in[0];
    const float* qk_emb    = (const float*)d_in[1];
    const float* qk_w      = (const float*)d_in[2];
    const float* v_emb     = (const float*)d_in[3];
    const float* v_w       = (const float*)d_in[4];
    const float* know_emb  = (const float*)d_in[5];
    const float* know_w    = (const float*)d_in[6];
    const float* tau_attn_k = (const float*)d_in[7];
    const float* tau_attn_b = (const float*)d_in[8];
    const float* tau_know_k = (const float*)d_in[9];
    const float* tau_know_b = (const float*)d_in[10];
    const float* expand_O  = (const float*)d_in[11];
    const float* ln1_s     = (const float*)d_in[12];
    const float* ln1_b     = (const float*)d_in[13];
    const float* ln2_s     = (const float*)d_in[14];
    const float* ln2_b     = (const float*)d_in[15];
    float* out = (float*)d_out;
    char*  ws  = (char*)d_ws;

    // workspace layout (bytes). NOTE: qkemb_bf and vemb_bf MUST stay adjacent
    // (merged N=8192 score GEMM treats them as one [8192][1024] matrix).
    u16*   nrm_bf   = (u16*)(ws + 0);                 //  8 MB
    u16*   qkemb_bf = (u16*)(ws + 8388608);           //  8 MB
    u16*   vemb_bf  = (u16*)(ws + 16777216);          //  8 MB (contiguous after qkemb!)
    u16*   knemb_bf = (u16*)(ws + 25165824);          // 16 MB
    u16*   expT_bf  = (u16*)(ws + 41943040);          //  2 MB
    u16*   attn_bf  = (u16*)(ws + 44040192);          //  8 MB
    u16*   qkw_bf   = (u16*)(ws + 52428800);          //  8 MB
    u16*   vw_bf    = (u16*)(ws + 60817408);          //  8 MB
    u16*   knw_bf   = (u16*)(ws + 69206016);          // 16 MB
    u16*   Qb       = (u16*)(ws + 85983232);          //  8 MB (bf16)
    u16*   Kb       = (u16*)(ws + 94371840);          //  8 MB (bf16)
    u16*   Vb       = (u16*)(ws + 102760448);         //  8 MB (bf16)
    u16*   keysbuf  = (u16*)(ws + 111149056);         // 64 MB (u16 keys, [TOK][8192])
    float* tauA     = (float*)(ws + 185384960);       // [T][3]
    float* tauKn    = (float*)(ws + 185434112);       // [T]
    float* colsum   = (float*)(ws + 185450496);       // 20480 floats: Q,K,V,Kn
    const size_t WS_NEEDED = 185532416;
    if (ws_size < WS_NEEDED) return;   // workspace too small — bail cleanly

    float* colQ = colsum, *colK = colsum + 4096, *colV = colsum + 8192, *colKn = colsum + 12288;

    hipMemsetAsync(colsum, 0, 20480 * sizeof(float), stream);
    hipMemsetAsync(out + (size_t)TOK * DIM, 0, sizeof(float), stream);

    // bf16 conversions: all six tables in one launch + expand_O transpose
    k_convert_all<<<2048, 256, 0, stream>>>(qk_emb, v_emb, know_emb, qk_w, v_w, know_w,
                                            qkemb_bf, vemb_bf, knemb_bf, qkw_bf, vw_bf, knw_bf);
    k_transpose_bf16<<<dim3(32, 32), 256, 0, stream>>>(expand_O, expT_bf);

    // LN1 + tau(3)
    k_ln_tau<<<TOK, 256, 0, stream>>>(x, ln1_s, ln1_b, tau_attn_k, tau_attn_b, 3, nrm_bf, tauA);

    // merged scores [qk | v] (u16 keys, N=8192): B = qkemb_bf ++ vemb_bf
    k_gemm_bt<0, 1><<<dim3(8192 / 128, TOK / 256), 512, 0, stream>>>(nrm_bf, qkemb_bf, keysbuf, TOK, 8192, DIM, nullptr);
    // fused gate+emit Q,K (cols 0..4095 of merged keys)
    k_gate_emit<1, 0><<<TOK, 256, NQK * sizeof(u16), stream>>>(keysbuf, 8192, NQK, 32, 0, tauA, 3, 0,
                                                               qkw_bf, Qb, Kb, nullptr, colQ, colK);
    // fused gate+emit V (cols 4096..8191)
    k_gate_emit<0, 0><<<TOK, 256, NV * sizeof(u16), stream>>>(keysbuf + 4096, 8192, NV, 32, 0, tauA, 3, 2,
                                                              vw_bf, Vb, nullptr, nullptr, colV, nullptr);

    // causal MHA (bf16 MFMA) -> bf16  (heavy q-tiles first via z relabel)
    k_attn<<<dim3(NH, 2, SLEN / 64), 256, 0, stream>>>(Qb, Kb, Vb, attn_bf);

    // out @ expand_O + residual x  -> x1 (stored in d_out)
    k_gemm_bt<2, 0><<<dim3(DIM / 128, TOK / 256), 512, 0, stream>>>(attn_bf, expT_bf, out, TOK, DIM, DIM, x);

    // LN2 + tau_know
    k_ln_tau<<<TOK, 256, 0, stream>>>(out, ln2_s, ln2_b, tau_know_k, tau_know_b, 1, nrm_bf, tauKn);

    // know scores (u16 keys) + fused gate+emit(+residual), full M in one shot
    k_gemm_bt<3, 1><<<dim3(NKN / 128, TOK / 256), 512, 0, stream>>>(nrm_bf, knemb_bf, keysbuf, TOK, NKN, DIM, nullptr);
    k_gate_emit<0, 1><<<TOK, 256, NKN * sizeof(u16), stream>>>(keysbuf, NKN, NKN, 64, 0, tauKn, 1, 0,
                                                               knw_bf, nullptr, nullptr, out, colKn, nullptr);

    // aux scalar
    k_aux<<<20, 256, 0, stream>>>(colsum, out + (size_t)TOK * DIM);
}